// Round 3
// baseline (192.560 us; speedup 1.0000x reference)
//
#include <hip/hip_runtime.h>
#include <hip/hip_bf16.h>

// ---------------------------------------------------------------------------
// LocalAttention: out = (softmax_mask(QK^T*s) V) Wo + bo, sliding causal W=256
// S=4096, D=1024, H=16, hd=64. bf16 MFMA (16x16x32), f32 accum.
// R3: BK=64 K-loop (half the barrier drains), XOR-swizzled LDS (kills the
//     8-way bank conflicts w/o padding), swapped-operand epilogue (float4/
//     ushort4 C-stores), XCD-aware dispatch (B-panel L2-hot), Wo 128x64 grid.
// ---------------------------------------------------------------------------

typedef __attribute__((ext_vector_type(8))) short bf16x8;
typedef __attribute__((ext_vector_type(4))) float f32x4;

#define S_LEN 4096
#define D_MODEL 1024
#define N_HEADS 16
#define HEAD_DIM 64
#define WINDOW 256
#define QKV_LD 3072

static __device__ __forceinline__ unsigned short f2bfbits(float f) {
    __hip_bfloat16 h = __float2bfloat16(f);
    unsigned short u;
    __builtin_memcpy(&u, &h, sizeof(u));
    return u;
}

typedef const __attribute__((address_space(1))) void c_gvoid;
typedef __attribute__((address_space(3))) void lvoid;
static __device__ __forceinline__ void gload16(const void* g, void* l) {
    __builtin_amdgcn_global_load_lds((c_gvoid*)g, (lvoid*)l, 16, 0, 0);
}

// ---------------- fused prep: x-cast, W transposes, bias concat -------------
__global__ __launch_bounds__(256) void prep_k(const float* __restrict__ x,
                                              const float* __restrict__ Wq,
                                              const float* __restrict__ Wk,
                                              const float* __restrict__ Wv,
                                              const float* __restrict__ Wo,
                                              const float* __restrict__ bq,
                                              const float* __restrict__ bk,
                                              const float* __restrict__ bv,
                                              unsigned short* __restrict__ xb,
                                              __hip_bfloat16* __restrict__ Wqkvt,
                                              __hip_bfloat16* __restrict__ Wot,
                                              float* __restrict__ bias_cat) {
    const int b = blockIdx.x;
    const int t = threadIdx.x;
    if (b < 2048) {
        int i = b * 2048 + t * 8;
        float4 v0 = *(const float4*)(x + i);
        float4 v1 = *(const float4*)(x + i + 4);
        ushort4 o0, o1;
        o0.x = f2bfbits(v0.x); o0.y = f2bfbits(v0.y);
        o0.z = f2bfbits(v0.z); o0.w = f2bfbits(v0.w);
        o1.x = f2bfbits(v1.x); o1.y = f2bfbits(v1.y);
        o1.z = f2bfbits(v1.z); o1.w = f2bfbits(v1.w);
        *(ushort4*)(xb + i) = o0;
        *(ushort4*)(xb + i + 4) = o1;
        return;
    }
    if (b < 3072) {
        __shared__ __hip_bfloat16 tile[64][65];
        const int m = (b - 2048) >> 8;
        const int tid = (b - 2048) & 255;
        const int n0 = (tid & 15) * 64, k0 = (tid >> 4) * 64;
        const float* src = (m == 0) ? Wq : (m == 1) ? Wk : (m == 2) ? Wv : Wo;
        __hip_bfloat16* dst = (m < 3) ? (Wqkvt + (size_t)m * D_MODEL * D_MODEL) : Wot;
        for (int c = t; c < 1024; c += 256) {
            int r = c >> 4, c4 = (c & 15) * 4;
            float4 v = *(const float4*)(src + (size_t)(k0 + r) * D_MODEL + n0 + c4);
            tile[r][c4 + 0] = __float2bfloat16(v.x);
            tile[r][c4 + 1] = __float2bfloat16(v.y);
            tile[r][c4 + 2] = __float2bfloat16(v.z);
            tile[r][c4 + 3] = __float2bfloat16(v.w);
        }
        __syncthreads();
        for (int c = t; c < 1024; c += 256) {
            int rr = c >> 4, c4 = (c & 15) * 4;
            ushort4 o;
            unsigned short u0, u1, u2, u3;
            __builtin_memcpy(&u0, &tile[c4 + 0][rr], 2);
            __builtin_memcpy(&u1, &tile[c4 + 1][rr], 2);
            __builtin_memcpy(&u2, &tile[c4 + 2][rr], 2);
            __builtin_memcpy(&u3, &tile[c4 + 3][rr], 2);
            o.x = u0; o.y = u1; o.z = u2; o.w = u3;
            *(ushort4*)((unsigned short*)dst + (size_t)(n0 + rr) * D_MODEL + k0 + c4) = o;
        }
        return;
    }
    for (int c = t; c < 3 * D_MODEL; c += 256) {
        float v = (c < 1024) ? bq[c] : (c < 2048) ? bk[c - 1024] : bv[c - 2048];
        bias_cat[c] = v;
    }
}

// ---------------- GEMM: C[M][N] = A[M][K] * Bt[N][K]^T + bias ---------------
// TMxTN tile, BK=64, 4 waves. LDS rows are 64 bf16 (128 B), no padding;
// 16B chunks XOR-swizzled by (row&7) -> 2-way-max bank aliasing (free).
// MFMA operands swapped: D row-index = N-dim -> 4 consecutive cols per lane
// -> vectorized C stores + float4 bias.
// NT_PER_XCD: XCD-aware dispatch (b&7 = xcd), each XCD owns NT_PER_XCD
// N-panels traversed M-fastest so the B-panel stays L2-hot.
template <int TM, int TN, int MI, int NI, bool OUT_BF16, int NT_PER_XCD>
__global__ __launch_bounds__(256) void gemm_bias_k(const __hip_bfloat16* __restrict__ A,
                                                   const __hip_bfloat16* __restrict__ Bt,
                                                   const float* __restrict__ bias,
                                                   void* __restrict__ Cout,
                                                   int M, int N, int K) {
    __shared__ __align__(16) __hip_bfloat16 As[TM * 64];
    __shared__ __align__(16) __hip_bfloat16 Bs[TN * 64];

    // XCD-aware block -> tile mapping
    const int b = blockIdx.x;
    const int xcd = b & 7, bi = b >> 3;
    const int mTiles = M / TM;
    const int nT = xcd * NT_PER_XCD + bi / mTiles;
    const int mT = bi % mTiles;
    const int m0 = mT * TM, n0 = nT * TN;

    const int t = threadIdx.x;
    const int wave = t >> 6, lane = t & 63;
    const int quad = lane >> 4, l16 = lane & 15;
    // wave sub-tile
    const int wm = (TN == 128) ? (wave & 1) * 64 : wave * (TM / 4);
    const int wn = (TN == 128) ? (wave >> 1) * 64 : 0;

    // staging coords: row = c*32 + t/8, swizzled 16B chunk = (t&7) ^ ((t>>3)&7)
    const int srow = t >> 3;
    const int gcol = (((t & 7) ^ ((t >> 3) & 7))) * 8;

    f32x4 acc[MI][NI];
#pragma unroll
    for (int mi = 0; mi < MI; ++mi)
#pragma unroll
        for (int ni = 0; ni < NI; ++ni) acc[mi][ni] = (f32x4){0.f, 0.f, 0.f, 0.f};

    const __hip_bfloat16* gA = A + (size_t)(m0 + srow) * K + gcol;
    const __hip_bfloat16* gB = Bt + (size_t)(n0 + srow) * K + gcol;

    for (int k0 = 0; k0 < K; k0 += 64) {
#pragma unroll
        for (int c = 0; c < TM / 32; ++c)
            gload16(gA + (size_t)c * 32 * K + k0, &As[c * 2048 + t * 8]);
#pragma unroll
        for (int c = 0; c < TN / 32; ++c)
            gload16(gB + (size_t)c * 32 * K + k0, &Bs[c * 2048 + t * 8]);
        __syncthreads();

#pragma unroll
        for (int kk = 0; kk < 2; ++kk) {
            bf16x8 af[MI], bfr[NI];
#pragma unroll
            for (int mi = 0; mi < MI; ++mi) {
                int row = wm + mi * 16 + l16;
                int phys = (kk * 4 + quad) ^ (row & 7);
                af[mi] = *(const bf16x8*)&As[row * 64 + phys * 8];
            }
#pragma unroll
            for (int ni = 0; ni < NI; ++ni) {
                int row = wn + ni * 16 + l16;
                int phys = (kk * 4 + quad) ^ (row & 7);
                bfr[ni] = *(const bf16x8*)&Bs[row * 64 + phys * 8];
            }
#pragma unroll
            for (int mi = 0; mi < MI; ++mi)
#pragma unroll
                for (int ni = 0; ni < NI; ++ni)
                    acc[mi][ni] = __builtin_amdgcn_mfma_f32_16x16x32_bf16(
                        bfr[ni], af[mi], acc[mi][ni], 0, 0, 0);
        }
        __syncthreads();
    }

    // epilogue (swapped layout): lane holds rows m = wm+mi*16+l16,
    // cols n = wn+ni*16+quad*4 + r (r=0..3 contiguous)
    float4 bv[NI];
#pragma unroll
    for (int ni = 0; ni < NI; ++ni)
        bv[ni] = *(const float4*)&bias[n0 + wn + ni * 16 + quad * 4];
#pragma unroll
    for (int mi = 0; mi < MI; ++mi) {
        const int row = m0 + wm + mi * 16 + l16;
#pragma unroll
        for (int ni = 0; ni < NI; ++ni) {
            const int col = n0 + wn + ni * 16 + quad * 4;
            if (OUT_BF16) {
                ushort4 o;
                o.x = f2bfbits(acc[mi][ni][0] + bv[ni].x);
                o.y = f2bfbits(acc[mi][ni][1] + bv[ni].y);
                o.z = f2bfbits(acc[mi][ni][2] + bv[ni].z);
                o.w = f2bfbits(acc[mi][ni][3] + bv[ni].w);
                *(ushort4*)((unsigned short*)Cout + (size_t)row * N + col) = o;
            } else {
                float4 o;
                o.x = acc[mi][ni][0] + bv[ni].x;
                o.y = acc[mi][ni][1] + bv[ni].y;
                o.z = acc[mi][ni][2] + bv[ni].z;
                o.w = acc[mi][ni][3] + bv[ni].w;
                *(float4*)((float*)Cout + (size_t)row * N + col) = o;
            }
        }
    }
}

// ---------------- sliding-window flash attention (unchanged from R2) --------
__global__ __launch_bounds__(256) void attn_k(const __hip_bfloat16* __restrict__ QKV,
                                              __hip_bfloat16* __restrict__ AO) {
    __shared__ __align__(16) __hip_bfloat16 Qs[64 * 72];
    __shared__ __align__(16) __hip_bfloat16 Ks[64 * 72];
    __shared__ __align__(16) __hip_bfloat16 Vt[64 * 72];
    __shared__ __align__(16) __hip_bfloat16 Ps[4 * 16 * 72];

    const int h = blockIdx.y;
    const int i0 = blockIdx.x * 64;
    const int t = threadIdx.x;
    const int wave = t >> 6, lane = t & 63;
    const int quad = lane >> 4, l16 = lane & 15;
    const float sc = 0.125f * 1.44269504088896f;

    const __hip_bfloat16* Q = QKV + h * HEAD_DIM;
    const __hip_bfloat16* K = QKV + D_MODEL + h * HEAD_DIM;
    const __hip_bfloat16* V = QKV + 2 * D_MODEL + h * HEAD_DIM;

    for (int c = t; c < 512; c += 256) {
        int row = c >> 3, c8 = (c & 7) * 8;
        *(uint4*)&Qs[row * 72 + c8] =
            *(const uint4*)(Q + (size_t)(i0 + row) * QKV_LD + c8);
    }
    __syncthreads();

    bf16x8 aq[2];
#pragma unroll
    for (int kk = 0; kk < 2; ++kk)
        aq[kk] = *(const bf16x8*)&Qs[(wave * 16 + l16) * 72 + kk * 32 + quad * 8];

    float mrow[4], lrow[4];
    f32x4 Ov[4];
#pragma unroll
    for (int r = 0; r < 4; ++r) { mrow[r] = -3.0e38f; lrow[r] = 0.f; }
#pragma unroll
    for (int no = 0; no < 4; ++no) Ov[no] = (f32x4){0.f, 0.f, 0.f, 0.f};

    const int vp = t >> 3, vc = t & 7;

    for (int tt = 0; tt < 5; ++tt) {
        const int tb = i0 - WINDOW + tt * 64;
        if (tb < 0) continue;

        for (int c = t; c < 512; c += 256) {
            int row = c >> 3, c8 = (c & 7) * 8;
            *(uint4*)&Ks[row * 72 + c8] =
                *(const uint4*)(K + (size_t)(tb + row) * QKV_LD + c8);
        }
        {
            uint4 v0 = *(const uint4*)(V + (size_t)(tb + 2 * vp) * QKV_LD + vc * 8);
            uint4 v1 = *(const uint4*)(V + (size_t)(tb + 2 * vp + 1) * QKV_LD + vc * 8);
            const unsigned short* a0 = (const unsigned short*)&v0;
            const unsigned short* a1 = (const unsigned short*)&v1;
#pragma unroll
            for (int j = 0; j < 8; ++j) {
                unsigned int pk = (unsigned int)a0[j] | ((unsigned int)a1[j] << 16);
                *(unsigned int*)&Vt[(vc * 8 + j) * 72 + 2 * vp] = pk;
            }
        }
        __syncthreads();

        f32x4 s[4];
#pragma unroll
        for (int ni = 0; ni < 4; ++ni) s[ni] = (f32x4){0.f, 0.f, 0.f, 0.f};
#pragma unroll
        for (int kk = 0; kk < 2; ++kk)
#pragma unroll
            for (int ni = 0; ni < 4; ++ni) {
                bf16x8 bk = *(const bf16x8*)&Ks[(ni * 16 + l16) * 72 + kk * 32 + quad * 8];
                s[ni] = __builtin_amdgcn_mfma_f32_16x16x32_bf16(aq[kk], bk, s[ni], 0, 0, 0);
            }

        const int irow0 = i0 + wave * 16 + quad * 4;
        float tv[4][4], rmax[4];
#pragma unroll
        for (int r = 0; r < 4; ++r) rmax[r] = -3.0e38f;
#pragma unroll
        for (int ni = 0; ni < 4; ++ni) {
            int j = tb + ni * 16 + l16;
#pragma unroll
            for (int r = 0; r < 4; ++r) {
                int i = irow0 + r;
                float v = s[ni][r] * sc;
                bool ok = (j <= i) && (i - j < WINDOW);
                v = ok ? v : -3.0e38f;
                tv[ni][r] = v;
                rmax[r] = fmaxf(rmax[r], v);
            }
        }
#pragma unroll
        for (int r = 0; r < 4; ++r) {
            rmax[r] = fmaxf(rmax[r], __shfl_xor(rmax[r], 1));
            rmax[r] = fmaxf(rmax[r], __shfl_xor(rmax[r], 2));
            rmax[r] = fmaxf(rmax[r], __shfl_xor(rmax[r], 4));
            rmax[r] = fmaxf(rmax[r], __shfl_xor(rmax[r], 8));
        }
        float alpha[4], rsum[4];
#pragma unroll
        for (int r = 0; r < 4; ++r) {
            float mn = fmaxf(mrow[r], rmax[r]);
            alpha[r] = exp2f(mrow[r] - mn);
            mrow[r] = mn;
            rsum[r] = 0.f;
        }
        float p[4][4];
#pragma unroll
        for (int ni = 0; ni < 4; ++ni)
#pragma unroll
            for (int r = 0; r < 4; ++r) {
                p[ni][r] = exp2f(tv[ni][r] - mrow[r]);
                rsum[r] += p[ni][r];
            }
#pragma unroll
        for (int r = 0; r < 4; ++r) {
            rsum[r] += __shfl_xor(rsum[r], 1);
            rsum[r] += __shfl_xor(rsum[r], 2);
            rsum[r] += __shfl_xor(rsum[r], 4);
            rsum[r] += __shfl_xor(rsum[r], 8);
            lrow[r] = lrow[r] * alpha[r] + rsum[r];
        }
#pragma unroll
        for (int no = 0; no < 4; ++no)
#pragma unroll
            for (int r = 0; r < 4; ++r) Ov[no][r] *= alpha[r];

#pragma unroll
        for (int ni = 0; ni < 4; ++ni)
#pragma unroll
            for (int r = 0; r < 4; ++r)
                Ps[(wave * 16 + quad * 4 + r) * 72 + ni * 16 + l16] =
                    __float2bfloat16(p[ni][r]);

#pragma unroll
        for (int kk = 0; kk < 2; ++kk) {
            bf16x8 ap = *(const bf16x8*)&Ps[(wave * 16 + l16) * 72 + kk * 32 + quad * 8];
#pragma unroll
            for (int no = 0; no < 4; ++no) {
                bf16x8 bvv = *(const bf16x8*)&Vt[(no * 16 + l16) * 72 + kk * 32 + quad * 8];
                Ov[no] = __builtin_amdgcn_mfma_f32_16x16x32_bf16(ap, bvv, Ov[no], 0, 0, 0);
            }
        }
        __syncthreads();
    }

    float inv[4];
#pragma unroll
    for (int r = 0; r < 4; ++r) inv[r] = 1.0f / lrow[r];
#pragma unroll
    for (int no = 0; no < 4; ++no)
#pragma unroll
        for (int r = 0; r < 4; ++r) {
            int i = i0 + wave * 16 + quad * 4 + r;
            AO[(size_t)i * D_MODEL + h * HEAD_DIM + no * 16 + l16] =
                __float2bfloat16(Ov[no][r] * inv[r]);
        }
}

// ---------------------------------------------------------------------------
extern "C" void kernel_launch(void* const* d_in, const int* in_sizes, int n_in,
                              void* d_out, int out_size, void* d_ws, size_t ws_size,
                              hipStream_t stream) {
    const float* x  = (const float*)d_in[0];
    const float* Wq = (const float*)d_in[1];
    const float* Wk = (const float*)d_in[2];
    const float* Wv = (const float*)d_in[3];
    const float* Wo = (const float*)d_in[4];
    const float* bq = (const float*)d_in[5];
    const float* bk = (const float*)d_in[6];
    const float* bv = (const float*)d_in[7];
    const float* bo = (const float*)d_in[8];
    float* out = (float*)d_out;

    char* w = (char*)d_ws;
    const size_t MB = 1u << 20;
    __hip_bfloat16* xb    = (__hip_bfloat16*)(w + 0 * MB);
    __hip_bfloat16* Wqkvt = (__hip_bfloat16*)(w + 8 * MB);
    __hip_bfloat16* Wot   = (__hip_bfloat16*)(w + 14 * MB);
    float*          bcat  = (float*)(w + 16 * MB);
    __hip_bfloat16* QKV   = (__hip_bfloat16*)(w + 17 * MB);
    __hip_bfloat16* AO    = (__hip_bfloat16*)(w + 41 * MB);

    prep_k<<<3073, 256, 0, stream>>>(x, Wq, Wk, Wv, Wo, bq, bk, bv,
                                     (unsigned short*)xb, Wqkvt, Wot, bcat);

    // fused QKV projection: 768 blocks, 24 n-tiles -> 3 per XCD
    gemm_bias_k<128, 128, 4, 4, true, 3><<<768, 256, 0, stream>>>(
        xb, Wqkvt, bcat, QKV, S_LEN, QKV_LD, D_MODEL);

    dim3 ag(S_LEN / 64, N_HEADS);
    attn_k<<<ag, 256, 0, stream>>>(QKV, AO);

    // output projection: 128x64 tiles, 512 blocks, 16 n-tiles -> 2 per XCD
    gemm_bias_k<128, 64, 2, 4, false, 2><<<512, 256, 0, stream>>>(
        AO, Wot, bo, out, S_LEN, D_MODEL, D_MODEL);
}

// Round 5
// 188.524 us; speedup vs baseline: 1.0214x; 1.0214x over previous
//
#include <hip/hip_runtime.h>
#include <hip/hip_bf16.h>

// ---------------------------------------------------------------------------
// LocalAttention: out = (softmax_mask(QK^T*s) V) Wo + bo, sliding causal W=256
// S=4096, D=1024, H=16, hd=64. bf16 MFMA (16x16x32), f32 accum.
// R5: R4 with attn staging offset fix (p*2048, was p*4096 -> LDS overflow +
//     unstaged K rows -> NaN). GEMM: BK=32, QKV 64x128 (1536 blocks ~6/CU),
//     Wo 64x64 (1024 blocks), XOR-4 swizzle (0 conflicts, gload-legal),
//     swapped-operand vectorized epilogue. Attention: swapped MFMAs -> one
//     q-row per lane (scalar softmax state, ushort4 stores), gload staging.
// ---------------------------------------------------------------------------

typedef __attribute__((ext_vector_type(8))) short bf16x8;
typedef __attribute__((ext_vector_type(4))) float f32x4;

#define S_LEN 4096
#define D_MODEL 1024
#define N_HEADS 16
#define HEAD_DIM 64
#define WINDOW 256
#define QKV_LD 3072

static __device__ __forceinline__ unsigned short f2bfbits(float f) {
    __hip_bfloat16 h = __float2bfloat16(f);
    unsigned short u;
    __builtin_memcpy(&u, &h, sizeof(u));
    return u;
}

typedef const __attribute__((address_space(1))) void c_gvoid;
typedef __attribute__((address_space(3))) void lvoid;
static __device__ __forceinline__ void gload16(const void* g, void* l) {
    __builtin_amdgcn_global_load_lds((c_gvoid*)g, (lvoid*)l, 16, 0, 0);
}

// ---------------- fused prep: x-cast, W transposes, bias concat -------------
__global__ __launch_bounds__(256) void prep_k(const float* __restrict__ x,
                                              const float* __restrict__ Wq,
                                              const float* __restrict__ Wk,
                                              const float* __restrict__ Wv,
                                              const float* __restrict__ Wo,
                                              const float* __restrict__ bq,
                                              const float* __restrict__ bk,
                                              const float* __restrict__ bv,
                                              unsigned short* __restrict__ xb,
                                              __hip_bfloat16* __restrict__ Wqkvt,
                                              __hip_bfloat16* __restrict__ Wot,
                                              float* __restrict__ bias_cat) {
    const int b = blockIdx.x;
    const int t = threadIdx.x;
    if (b < 2048) {
        int i = b * 2048 + t * 8;
        float4 v0 = *(const float4*)(x + i);
        float4 v1 = *(const float4*)(x + i + 4);
        ushort4 o0, o1;
        o0.x = f2bfbits(v0.x); o0.y = f2bfbits(v0.y);
        o0.z = f2bfbits(v0.z); o0.w = f2bfbits(v0.w);
        o1.x = f2bfbits(v1.x); o1.y = f2bfbits(v1.y);
        o1.z = f2bfbits(v1.z); o1.w = f2bfbits(v1.w);
        *(ushort4*)(xb + i) = o0;
        *(ushort4*)(xb + i + 4) = o1;
        return;
    }
    if (b < 3072) {
        __shared__ __hip_bfloat16 tile[64][65];
        const int m = (b - 2048) >> 8;
        const int tid = (b - 2048) & 255;
        const int n0 = (tid & 15) * 64, k0 = (tid >> 4) * 64;
        const float* src = (m == 0) ? Wq : (m == 1) ? Wk : (m == 2) ? Wv : Wo;
        __hip_bfloat16* dst = (m < 3) ? (Wqkvt + (size_t)m * D_MODEL * D_MODEL) : Wot;
        for (int c = t; c < 1024; c += 256) {
            int r = c >> 4, c4 = (c & 15) * 4;
            float4 v = *(const float4*)(src + (size_t)(k0 + r) * D_MODEL + n0 + c4);
            tile[r][c4 + 0] = __float2bfloat16(v.x);
            tile[r][c4 + 1] = __float2bfloat16(v.y);
            tile[r][c4 + 2] = __float2bfloat16(v.z);
            tile[r][c4 + 3] = __float2bfloat16(v.w);
        }
        __syncthreads();
        for (int c = t; c < 1024; c += 256) {
            int rr = c >> 4, c4 = (c & 15) * 4;
            ushort4 o;
            unsigned short u0, u1, u2, u3;
            __builtin_memcpy(&u0, &tile[c4 + 0][rr], 2);
            __builtin_memcpy(&u1, &tile[c4 + 1][rr], 2);
            __builtin_memcpy(&u2, &tile[c4 + 2][rr], 2);
            __builtin_memcpy(&u3, &tile[c4 + 3][rr], 2);
            o.x = u0; o.y = u1; o.z = u2; o.w = u3;
            *(ushort4*)((unsigned short*)dst + (size_t)(n0 + rr) * D_MODEL + k0 + c4) = o;
        }
        return;
    }
    for (int c = t; c < 3 * D_MODEL; c += 256) {
        float v = (c < 1024) ? bq[c] : (c < 2048) ? bk[c - 1024] : bv[c - 2048];
        bias_cat[c] = v;
    }
}

// ---------------- GEMM: C[M][N] = A[M][K] * Bt[N][K]^T + bias ---------------
// BK=32 (rows = 32 bf16 = 64 B). 16B chunks XOR-swizzled: lds slot s at row r
// holds logical chunk s ^ (r&3) ^ ((r>>2)&3)  ->  <=2-way bank aliasing, and
// staging stays gload-legal (swizzle applied to the GLOBAL address per lane).
// MFMA operands swapped -> lane's 4 acc elems = 4 consecutive N-cols.
template <int TM, int TN, bool OUT_BF16>
__global__ __launch_bounds__(256) void gemm_bias_k(const __hip_bfloat16* __restrict__ A,
                                                   const __hip_bfloat16* __restrict__ Bt,
                                                   const float* __restrict__ bias,
                                                   void* __restrict__ Cout,
                                                   int M, int N, int K) {
    constexpr int MI = TM / 32;   // frags per wave along M (wave = TM/2 rows)
    constexpr int NI = TN / 32;
    __shared__ __align__(16) __hip_bfloat16 As[TM * 32];
    __shared__ __align__(16) __hip_bfloat16 Bs[TN * 32];

    const int m0 = blockIdx.y * TM, n0 = blockIdx.x * TN;
    const int t = threadIdx.x;
    const int wave = t >> 6, lane = t & 63;
    const int quad = lane >> 4, l16 = lane & 15;
    const int wm = (wave & 1) * (TM / 2), wn = (wave >> 1) * (TN / 2);

    // staging: pass of 2048 elems = 64 rows x 4 chunks; row = t>>2, slot = t&3
    const int srow = t >> 2;
    const int gcol = ((t & 3) ^ ((t >> 2) & 3) ^ ((t >> 4) & 3)) * 8;

    f32x4 acc[MI][NI];
#pragma unroll
    for (int mi = 0; mi < MI; ++mi)
#pragma unroll
        for (int ni = 0; ni < NI; ++ni) acc[mi][ni] = (f32x4){0.f, 0.f, 0.f, 0.f};

    const __hip_bfloat16* gA = A + (size_t)(m0 + srow) * K + gcol;
    const __hip_bfloat16* gB = Bt + (size_t)(n0 + srow) * K + gcol;

    for (int k0 = 0; k0 < K; k0 += 32) {
#pragma unroll
        for (int c = 0; c < TM / 64; ++c)
            gload16(gA + (size_t)(c * 64) * K + k0, &As[c * 2048 + t * 8]);
#pragma unroll
        for (int c = 0; c < TN / 64; ++c)
            gload16(gB + (size_t)(c * 64) * K + k0, &Bs[c * 2048 + t * 8]);
        __syncthreads();

        bf16x8 af[MI], bfr[NI];
#pragma unroll
        for (int mi = 0; mi < MI; ++mi) {
            int r = wm + mi * 16 + l16;
            int phys = quad ^ (r & 3) ^ ((r >> 2) & 3);
            af[mi] = *(const bf16x8*)&As[r * 32 + phys * 8];
        }
#pragma unroll
        for (int ni = 0; ni < NI; ++ni) {
            int r = wn + ni * 16 + l16;
            int phys = quad ^ (r & 3) ^ ((r >> 2) & 3);
            bfr[ni] = *(const bf16x8*)&Bs[r * 32 + phys * 8];
        }
#pragma unroll
        for (int mi = 0; mi < MI; ++mi)
#pragma unroll
            for (int ni = 0; ni < NI; ++ni)
                acc[mi][ni] = __builtin_amdgcn_mfma_f32_16x16x32_bf16(
                    bfr[ni], af[mi], acc[mi][ni], 0, 0, 0);
        __syncthreads();
    }

    // epilogue: rows m = wm+mi*16+l16; cols n = wn+ni*16+quad*4 + (0..3)
    float4 bv[NI];
#pragma unroll
    for (int ni = 0; ni < NI; ++ni)
        bv[ni] = *(const float4*)&bias[n0 + wn + ni * 16 + quad * 4];
#pragma unroll
    for (int mi = 0; mi < MI; ++mi) {
        const int row = m0 + wm + mi * 16 + l16;
#pragma unroll
        for (int ni = 0; ni < NI; ++ni) {
            const int col = n0 + wn + ni * 16 + quad * 4;
            if (OUT_BF16) {
                ushort4 o;
                o.x = f2bfbits(acc[mi][ni][0] + bv[ni].x);
                o.y = f2bfbits(acc[mi][ni][1] + bv[ni].y);
                o.z = f2bfbits(acc[mi][ni][2] + bv[ni].z);
                o.w = f2bfbits(acc[mi][ni][3] + bv[ni].w);
                *(ushort4*)((unsigned short*)Cout + (size_t)row * N + col) = o;
            } else {
                float4 o;
                o.x = acc[mi][ni][0] + bv[ni].x;
                o.y = acc[mi][ni][1] + bv[ni].y;
                o.z = acc[mi][ni][2] + bv[ni].z;
                o.w = acc[mi][ni][3] + bv[ni].w;
                *(float4*)((float*)Cout + (size_t)row * N + col) = o;
            }
        }
    }
}

// ---------------- sliding-window flash attention (swapped layout) -----------
// block: 1 head x 64 q (4 waves x 16 q). Both MFMAs operand-swapped so each
// lane owns exactly one q-row (q = wave*16 + l16): softmax m/l/alpha are lane
// scalars, cross-quad reduce = 2 shuffles, P & O stores are ushort4.
__global__ __launch_bounds__(256) void attn_k(const __hip_bfloat16* __restrict__ QKV,
                                              __hip_bfloat16* __restrict__ AO) {
    __shared__ __align__(16) __hip_bfloat16 Qs[64 * 64];
    __shared__ __align__(16) __hip_bfloat16 Ks[64 * 64];
    __shared__ __align__(16) __hip_bfloat16 Vt[64 * 72];  // [hd][key], padded
    __shared__ __align__(16) __hip_bfloat16 Ps[64 * 72];  // [q][key], padded

    const int h = blockIdx.y;
    const int i0 = blockIdx.x * 64;
    const int t = threadIdx.x;
    const int wave = t >> 6, lane = t & 63;
    const int quad = lane >> 4, l16 = lane & 15;
    const float sc = 0.125f * 1.44269504088896f;  // 1/sqrt(64) * log2(e)

    const __hip_bfloat16* Q = QKV + h * HEAD_DIM;
    const __hip_bfloat16* K = QKV + D_MODEL + h * HEAD_DIM;
    const __hip_bfloat16* V = QKV + 2 * D_MODEL + h * HEAD_DIM;

    // stage Q via gload (swizzle-8 on 64-elem rows), 2 passes of 32 rows
    // each pass covers 32 rows x 64 cols = 2048 elems (256 lanes x 8)
    const int grow = t >> 3;                       // 0..31
    const int glog = ((t & 7) ^ ((t >> 3) & 7)) * 8;
#pragma unroll
    for (int p = 0; p < 2; ++p)
        gload16(Q + (size_t)(i0 + p * 32 + grow) * QKV_LD + glog,
                &Qs[p * 2048 + t * 8]);
    __syncthreads();

    const int rq = wave * 16 + l16;   // this lane's q row (block-relative)
    const int qi = i0 + rq;           // absolute q index
    bf16x8 aq[2];
#pragma unroll
    for (int kk = 0; kk < 2; ++kk)
        aq[kk] = *(const bf16x8*)&Qs[rq * 64 + ((kk * 4 + quad) ^ (rq & 7)) * 8];

    float m_i = -3.0e38f, l_i = 0.f;
    f32x4 Ov[4];
#pragma unroll
    for (int no = 0; no < 4; ++no) Ov[no] = (f32x4){0.f, 0.f, 0.f, 0.f};

    const int vp = t >> 3, vc = t & 7;

    for (int tt = 0; tt < 5; ++tt) {
        const int tb = i0 - WINDOW + tt * 64;
        if (tb < 0) continue;  // uniform across block

        // stage K via gload (2 passes of 32 rows, 2048 elems each)
#pragma unroll
        for (int p = 0; p < 2; ++p)
            gload16(K + (size_t)(tb + p * 32 + grow) * QKV_LD + glog,
                    &Ks[p * 2048 + t * 8]);
        // stage V transposed (2 rows packed per b32 write)
        {
            uint4 v0 = *(const uint4*)(V + (size_t)(tb + 2 * vp) * QKV_LD + vc * 8);
            uint4 v1 = *(const uint4*)(V + (size_t)(tb + 2 * vp + 1) * QKV_LD + vc * 8);
            const unsigned short* a0 = (const unsigned short*)&v0;
            const unsigned short* a1 = (const unsigned short*)&v1;
#pragma unroll
            for (int j = 0; j < 8; ++j) {
                unsigned int pk = (unsigned int)a0[j] | ((unsigned int)a1[j] << 16);
                *(unsigned int*)&Vt[(vc * 8 + j) * 72 + 2 * vp] = pk;
            }
        }
        __syncthreads();

        // S' = K Q^T (swapped): lane holds keys ni*16+quad*4+(0..3) for q=qi
        f32x4 s[4];
#pragma unroll
        for (int ni = 0; ni < 4; ++ni) s[ni] = (f32x4){0.f, 0.f, 0.f, 0.f};
#pragma unroll
        for (int kk = 0; kk < 2; ++kk)
#pragma unroll
            for (int ni = 0; ni < 4; ++ni) {
                int rk = ni * 16 + l16;
                bf16x8 bk = *(const bf16x8*)&Ks[rk * 64 + ((kk * 4 + quad) ^ (rk & 7)) * 8];
                s[ni] = __builtin_amdgcn_mfma_f32_16x16x32_bf16(bk, aq[kk], s[ni], 0, 0, 0);
            }

        // mask + online softmax (lane-scalar state)
        float p[4][4], mx = -3.0e38f;
#pragma unroll
        for (int ni = 0; ni < 4; ++ni)
#pragma unroll
            for (int r = 0; r < 4; ++r) {
                int j = tb + ni * 16 + quad * 4 + r;
                float v = s[ni][r] * sc;
                bool ok = (j <= qi) && (qi - j < WINDOW);
                v = ok ? v : -3.0e38f;
                p[ni][r] = v;
                mx = fmaxf(mx, v);
            }
        mx = fmaxf(mx, __shfl_xor(mx, 16));
        mx = fmaxf(mx, __shfl_xor(mx, 32));
        const float mn = fmaxf(m_i, mx);
        const float alpha = exp2f(m_i - mn);
        m_i = mn;
        float sum = 0.f;
#pragma unroll
        for (int ni = 0; ni < 4; ++ni)
#pragma unroll
            for (int r = 0; r < 4; ++r) {
                float e = exp2f(p[ni][r] - mn);
                p[ni][r] = e;
                sum += e;
            }
        sum += __shfl_xor(sum, 16);
        sum += __shfl_xor(sum, 32);
        l_i = l_i * alpha + sum;
#pragma unroll
        for (int no = 0; no < 4; ++no) Ov[no] *= alpha;

        // P' -> Ps in A-layout: row = q (rq), cols = 4 consecutive keys
#pragma unroll
        for (int ni = 0; ni < 4; ++ni) {
            ushort4 w4;
            w4.x = f2bfbits(p[ni][0]); w4.y = f2bfbits(p[ni][1]);
            w4.z = f2bfbits(p[ni][2]); w4.w = f2bfbits(p[ni][3]);
            *(ushort4*)&Ps[rq * 72 + ni * 16 + quad * 4] = w4;
        }

        // O' += V^T P^T (swapped): lane gets hd = no*16+quad*4+(0..3), q = qi
#pragma unroll
        for (int kk = 0; kk < 2; ++kk) {
            bf16x8 ap = *(const bf16x8*)&Ps[rq * 72 + kk * 32 + quad * 8];
#pragma unroll
            for (int no = 0; no < 4; ++no) {
                bf16x8 bvv = *(const bf16x8*)&Vt[(no * 16 + l16) * 72 + kk * 32 + quad * 8];
                Ov[no] = __builtin_amdgcn_mfma_f32_16x16x32_bf16(bvv, ap, Ov[no], 0, 0, 0);
            }
        }
        __syncthreads();  // protect Ks/Vt before next tile's staging
    }

    // normalize + vectorized store (4 consecutive hd per reg group)
    const float inv = 1.0f / l_i;
#pragma unroll
    for (int no = 0; no < 4; ++no) {
        ushort4 o;
        o.x = f2bfbits(Ov[no][0] * inv);
        o.y = f2bfbits(Ov[no][1] * inv);
        o.z = f2bfbits(Ov[no][2] * inv);
        o.w = f2bfbits(Ov[no][3] * inv);
        *(ushort4*)((unsigned short*)AO + (size_t)qi * D_MODEL + h * HEAD_DIM +
                    no * 16 + quad * 4) = o;
    }
}

// ---------------------------------------------------------------------------
extern "C" void kernel_launch(void* const* d_in, const int* in_sizes, int n_in,
                              void* d_out, int out_size, void* d_ws, size_t ws_size,
                              hipStream_t stream) {
    const float* x  = (const float*)d_in[0];
    const float* Wq = (const float*)d_in[1];
    const float* Wk = (const float*)d_in[2];
    const float* Wv = (const float*)d_in[3];
    const float* Wo = (const float*)d_in[4];
    const float* bq = (const float*)d_in[5];
    const float* bk = (const float*)d_in[6];
    const float* bv = (const float*)d_in[7];
    const float* bo = (const float*)d_in[8];
    float* out = (float*)d_out;

    char* w = (char*)d_ws;
    const size_t MB = 1u << 20;
    __hip_bfloat16* xb    = (__hip_bfloat16*)(w + 0 * MB);   // 8 MB
    __hip_bfloat16* Wqkvt = (__hip_bfloat16*)(w + 8 * MB);   // 6 MB [3072][1024]
    __hip_bfloat16* Wot   = (__hip_bfloat16*)(w + 14 * MB);  // 2 MB
    float*          bcat  = (float*)(w + 16 * MB);           // 12 KB
    __hip_bfloat16* QKV   = (__hip_bfloat16*)(w + 17 * MB);  // 24 MB [4096][3072]
    __hip_bfloat16* AO    = (__hip_bfloat16*)(w + 41 * MB);  // 8 MB, end 49 MB

    prep_k<<<3073, 256, 0, stream>>>(x, Wq, Wk, Wv, Wo, bq, bk, bv,
                                     (unsigned short*)xb, Wqkvt, Wot, bcat);

    // fused QKV projection: 64x128 tiles, grid (24, 64) = 1536 blocks
    dim3 gqkv(QKV_LD / 128, S_LEN / 64);
    gemm_bias_k<64, 128, true><<<gqkv, 256, 0, stream>>>(
        xb, Wqkvt, bcat, QKV, S_LEN, QKV_LD, D_MODEL);

    dim3 ag(S_LEN / 64, N_HEADS);
    attn_k<<<ag, 256, 0, stream>>>(QKV, AO);

    // output projection: 64x64 tiles, grid (16, 64) = 1024 blocks
    dim3 go(D_MODEL / 64, S_LEN / 64);
    gemm_bias_k<64, 64, false><<<go, 256, 0, stream>>>(
        AO, Wot, bo, out, S_LEN, D_MODEL, D_MODEL);
}

// Round 6
// 179.917 us; speedup vs baseline: 1.0703x; 1.0478x over previous
//
#include <hip/hip_runtime.h>
#include <hip/hip_bf16.h>

// ---------------------------------------------------------------------------
// LocalAttention: out = (softmax_mask(QK^T*s) V) Wo + bo, sliding causal W=256
// S=4096, D=1024, H=16, hd=64. bf16 MFMA (16x16x32), f32 accum.
// R6: GEMM = 128x128 tile (R2's best), linear grid (R2's FETCH), BK=64
//     (half the barrier drains vs BK=32), 128B-pitch LDS rows + XOR-8 chunk
//     swizzle (R3-proven 0 conflicts; bank = f(chunk) only, row-independent).
//     Wo GEMM 128x64. Attention unchanged from R5 (passes, <60us).
// Evidence log: conflicts counter is device-wide (~1-2us impact, red
// herring); barrier amortization is the lever (R5 halved work/barrier ->
// +35% time); XCD-pinned grid thrashes L2 (R3 FETCH 36->69MB).
// ---------------------------------------------------------------------------

typedef __attribute__((ext_vector_type(8))) short bf16x8;
typedef __attribute__((ext_vector_type(4))) float f32x4;

#define S_LEN 4096
#define D_MODEL 1024
#define N_HEADS 16
#define HEAD_DIM 64
#define WINDOW 256
#define QKV_LD 3072

static __device__ __forceinline__ unsigned short f2bfbits(float f) {
    __hip_bfloat16 h = __float2bfloat16(f);
    unsigned short u;
    __builtin_memcpy(&u, &h, sizeof(u));
    return u;
}

typedef const __attribute__((address_space(1))) void c_gvoid;
typedef __attribute__((address_space(3))) void lvoid;
static __device__ __forceinline__ void gload16(const void* g, void* l) {
    __builtin_amdgcn_global_load_lds((c_gvoid*)g, (lvoid*)l, 16, 0, 0);
}

// ---------------- fused prep: x-cast, W transposes, bias concat -------------
__global__ __launch_bounds__(256) void prep_k(const float* __restrict__ x,
                                              const float* __restrict__ Wq,
                                              const float* __restrict__ Wk,
                                              const float* __restrict__ Wv,
                                              const float* __restrict__ Wo,
                                              const float* __restrict__ bq,
                                              const float* __restrict__ bk,
                                              const float* __restrict__ bv,
                                              unsigned short* __restrict__ xb,
                                              __hip_bfloat16* __restrict__ Wqkvt,
                                              __hip_bfloat16* __restrict__ Wot,
                                              float* __restrict__ bias_cat) {
    const int b = blockIdx.x;
    const int t = threadIdx.x;
    if (b < 2048) {
        int i = b * 2048 + t * 8;
        float4 v0 = *(const float4*)(x + i);
        float4 v1 = *(const float4*)(x + i + 4);
        ushort4 o0, o1;
        o0.x = f2bfbits(v0.x); o0.y = f2bfbits(v0.y);
        o0.z = f2bfbits(v0.z); o0.w = f2bfbits(v0.w);
        o1.x = f2bfbits(v1.x); o1.y = f2bfbits(v1.y);
        o1.z = f2bfbits(v1.z); o1.w = f2bfbits(v1.w);
        *(ushort4*)(xb + i) = o0;
        *(ushort4*)(xb + i + 4) = o1;
        return;
    }
    if (b < 3072) {
        __shared__ __hip_bfloat16 tile[64][65];
        const int m = (b - 2048) >> 8;
        const int tid = (b - 2048) & 255;
        const int n0 = (tid & 15) * 64, k0 = (tid >> 4) * 64;
        const float* src = (m == 0) ? Wq : (m == 1) ? Wk : (m == 2) ? Wv : Wo;
        __hip_bfloat16* dst = (m < 3) ? (Wqkvt + (size_t)m * D_MODEL * D_MODEL) : Wot;
        for (int c = t; c < 1024; c += 256) {
            int r = c >> 4, c4 = (c & 15) * 4;
            float4 v = *(const float4*)(src + (size_t)(k0 + r) * D_MODEL + n0 + c4);
            tile[r][c4 + 0] = __float2bfloat16(v.x);
            tile[r][c4 + 1] = __float2bfloat16(v.y);
            tile[r][c4 + 2] = __float2bfloat16(v.z);
            tile[r][c4 + 3] = __float2bfloat16(v.w);
        }
        __syncthreads();
        for (int c = t; c < 1024; c += 256) {
            int rr = c >> 4, c4 = (c & 15) * 4;
            ushort4 o;
            unsigned short u0, u1, u2, u3;
            __builtin_memcpy(&u0, &tile[c4 + 0][rr], 2);
            __builtin_memcpy(&u1, &tile[c4 + 1][rr], 2);
            __builtin_memcpy(&u2, &tile[c4 + 2][rr], 2);
            __builtin_memcpy(&u3, &tile[c4 + 3][rr], 2);
            o.x = u0; o.y = u1; o.z = u2; o.w = u3;
            *(ushort4*)((unsigned short*)dst + (size_t)(n0 + rr) * D_MODEL + k0 + c4) = o;
        }
        return;
    }
    for (int c = t; c < 3 * D_MODEL; c += 256) {
        float v = (c < 1024) ? bq[c] : (c < 2048) ? bk[c - 1024] : bv[c - 2048];
        bias_cat[c] = v;
    }
}

// ---------------- GEMM: C[M][N] = A[M][K] * Bt[N][K]^T + bias ---------------
// BK=64: LDS rows are 64 bf16 = 128 B (all 32 banks) -> bank index depends
// only on the 16B chunk, never on the row. XOR-8 swizzle: phys chunk s at
// row r holds logical chunk s^(r&7) (R3-measured: 0 bank conflicts).
// Staging via global_load_lds w=16; swizzle applied on the GLOBAL side so the
// LDS destination stays the required wave-uniform base + lane*16.
// MFMA operands swapped -> lane's 4 acc elems = 4 consecutive N-cols.
template <int TM, int TN, bool OUT_BF16>
__global__ __launch_bounds__(256) void gemm_bias_k(const __hip_bfloat16* __restrict__ A,
                                                   const __hip_bfloat16* __restrict__ Bt,
                                                   const float* __restrict__ bias,
                                                   void* __restrict__ Cout,
                                                   int M, int N, int K) {
    constexpr int MI = TM / 32;   // wave covers TM/2 rows -> MI 16-row frags
    constexpr int NI = TN / 32;
    __shared__ __align__(16) __hip_bfloat16 As[TM * 64];
    __shared__ __align__(16) __hip_bfloat16 Bs[TN * 64];

    const int m0 = blockIdx.y * TM, n0 = blockIdx.x * TN;
    const int t = threadIdx.x;
    const int wave = t >> 6, lane = t & 63;
    const int quad = lane >> 4, l16 = lane & 15;
    const int wm = (wave & 1) * (TM / 2), wn = (wave >> 1) * (TN / 2);

    // staging: one pass = 32 rows x 8 chunks (2048 elems); row = t>>3,
    // global chunk = (t&7) ^ (row&7)  [LDS slot t&7 <- logical chunk]
    const int srow = t >> 3;
    const int gcol = ((t & 7) ^ (srow & 7)) * 8;

    f32x4 acc[MI][NI];
#pragma unroll
    for (int mi = 0; mi < MI; ++mi)
#pragma unroll
        for (int ni = 0; ni < NI; ++ni) acc[mi][ni] = (f32x4){0.f, 0.f, 0.f, 0.f};

    const __hip_bfloat16* gA = A + (size_t)(m0 + srow) * K + gcol;
    const __hip_bfloat16* gB = Bt + (size_t)(n0 + srow) * K + gcol;

    for (int k0 = 0; k0 < K; k0 += 64) {
#pragma unroll
        for (int p = 0; p < TM / 32; ++p)
            gload16(gA + (size_t)(p * 32) * K + k0, &As[p * 2048 + t * 8]);
#pragma unroll
        for (int p = 0; p < TN / 32; ++p)
            gload16(gB + (size_t)(p * 32) * K + k0, &Bs[p * 2048 + t * 8]);
        __syncthreads();

#pragma unroll
        for (int kk = 0; kk < 2; ++kk) {
            bf16x8 af[MI], bfr[NI];
#pragma unroll
            for (int mi = 0; mi < MI; ++mi) {
                int r = wm + mi * 16 + l16;
                int phys = (kk * 4 + quad) ^ (r & 7);
                af[mi] = *(const bf16x8*)&As[r * 64 + phys * 8];
            }
#pragma unroll
            for (int ni = 0; ni < NI; ++ni) {
                int r = wn + ni * 16 + l16;
                int phys = (kk * 4 + quad) ^ (r & 7);
                bfr[ni] = *(const bf16x8*)&Bs[r * 64 + phys * 8];
            }
#pragma unroll
            for (int mi = 0; mi < MI; ++mi)
#pragma unroll
                for (int ni = 0; ni < NI; ++ni)
                    acc[mi][ni] = __builtin_amdgcn_mfma_f32_16x16x32_bf16(
                        bfr[ni], af[mi], acc[mi][ni], 0, 0, 0);
        }
        __syncthreads();
    }

    // epilogue: rows m = wm+mi*16+l16; cols n = wn+ni*16+quad*4 + (0..3)
    float4 bv[NI];
#pragma unroll
    for (int ni = 0; ni < NI; ++ni)
        bv[ni] = *(const float4*)&bias[n0 + wn + ni * 16 + quad * 4];
#pragma unroll
    for (int mi = 0; mi < MI; ++mi) {
        const int row = m0 + wm + mi * 16 + l16;
#pragma unroll
        for (int ni = 0; ni < NI; ++ni) {
            const int col = n0 + wn + ni * 16 + quad * 4;
            if (OUT_BF16) {
                ushort4 o;
                o.x = f2bfbits(acc[mi][ni][0] + bv[ni].x);
                o.y = f2bfbits(acc[mi][ni][1] + bv[ni].y);
                o.z = f2bfbits(acc[mi][ni][2] + bv[ni].z);
                o.w = f2bfbits(acc[mi][ni][3] + bv[ni].w);
                *(ushort4*)((unsigned short*)Cout + (size_t)row * N + col) = o;
            } else {
                float4 o;
                o.x = acc[mi][ni][0] + bv[ni].x;
                o.y = acc[mi][ni][1] + bv[ni].y;
                o.z = acc[mi][ni][2] + bv[ni].z;
                o.w = acc[mi][ni][3] + bv[ni].w;
                *(float4*)((float*)Cout + (size_t)row * N + col) = o;
            }
        }
    }
}

// ---------------- sliding-window flash attention (swapped layout) -----------
// block: 1 head x 64 q (4 waves x 16 q). Both MFMAs operand-swapped so each
// lane owns exactly one q-row: softmax m/l/alpha are lane scalars, cross-quad
// reduce = 2 shuffles, P & O stores are ushort4.
__global__ __launch_bounds__(256) void attn_k(const __hip_bfloat16* __restrict__ QKV,
                                              __hip_bfloat16* __restrict__ AO) {
    __shared__ __align__(16) __hip_bfloat16 Qs[64 * 64];
    __shared__ __align__(16) __hip_bfloat16 Ks[64 * 64];
    __shared__ __align__(16) __hip_bfloat16 Vt[64 * 72];  // [hd][key], padded
    __shared__ __align__(16) __hip_bfloat16 Ps[64 * 72];  // [q][key], padded

    const int h = blockIdx.y;
    const int i0 = blockIdx.x * 64;
    const int t = threadIdx.x;
    const int wave = t >> 6, lane = t & 63;
    const int quad = lane >> 4, l16 = lane & 15;
    const float sc = 0.125f * 1.44269504088896f;  // 1/sqrt(64) * log2(e)

    const __hip_bfloat16* Q = QKV + h * HEAD_DIM;
    const __hip_bfloat16* K = QKV + D_MODEL + h * HEAD_DIM;
    const __hip_bfloat16* V = QKV + 2 * D_MODEL + h * HEAD_DIM;

    // stage Q via gload (swizzle-8 on 64-elem rows), 2 passes of 32 rows
    const int grow = t >> 3;                       // 0..31
    const int glog = ((t & 7) ^ ((t >> 3) & 7)) * 8;
#pragma unroll
    for (int p = 0; p < 2; ++p)
        gload16(Q + (size_t)(i0 + p * 32 + grow) * QKV_LD + glog,
                &Qs[p * 2048 + t * 8]);
    __syncthreads();

    const int rq = wave * 16 + l16;   // this lane's q row (block-relative)
    const int qi = i0 + rq;           // absolute q index
    bf16x8 aq[2];
#pragma unroll
    for (int kk = 0; kk < 2; ++kk)
        aq[kk] = *(const bf16x8*)&Qs[rq * 64 + ((kk * 4 + quad) ^ (rq & 7)) * 8];

    float m_i = -3.0e38f, l_i = 0.f;
    f32x4 Ov[4];
#pragma unroll
    for (int no = 0; no < 4; ++no) Ov[no] = (f32x4){0.f, 0.f, 0.f, 0.f};

    const int vp = t >> 3, vc = t & 7;

    for (int tt = 0; tt < 5; ++tt) {
        const int tb = i0 - WINDOW + tt * 64;
        if (tb < 0) continue;  // uniform across block

        // stage K via gload (2 passes of 32 rows, 2048 elems each)
#pragma unroll
        for (int p = 0; p < 2; ++p)
            gload16(K + (size_t)(tb + p * 32 + grow) * QKV_LD + glog,
                    &Ks[p * 2048 + t * 8]);
        // stage V transposed (2 rows packed per b32 write)
        {
            uint4 v0 = *(const uint4*)(V + (size_t)(tb + 2 * vp) * QKV_LD + vc * 8);
            uint4 v1 = *(const uint4*)(V + (size_t)(tb + 2 * vp + 1) * QKV_LD + vc * 8);
            const unsigned short* a0 = (const unsigned short*)&v0;
            const unsigned short* a1 = (const unsigned short*)&v1;
#pragma unroll
            for (int j = 0; j < 8; ++j) {
                unsigned int pk = (unsigned int)a0[j] | ((unsigned int)a1[j] << 16);
                *(unsigned int*)&Vt[(vc * 8 + j) * 72 + 2 * vp] = pk;
            }
        }
        __syncthreads();

        // S' = K Q^T (swapped): lane holds keys ni*16+quad*4+(0..3) for q=qi
        f32x4 s[4];
#pragma unroll
        for (int ni = 0; ni < 4; ++ni) s[ni] = (f32x4){0.f, 0.f, 0.f, 0.f};
#pragma unroll
        for (int kk = 0; kk < 2; ++kk)
#pragma unroll
            for (int ni = 0; ni < 4; ++ni) {
                int rk = ni * 16 + l16;
                bf16x8 bk = *(const bf16x8*)&Ks[rk * 64 + ((kk * 4 + quad) ^ (rk & 7)) * 8];
                s[ni] = __builtin_amdgcn_mfma_f32_16x16x32_bf16(bk, aq[kk], s[ni], 0, 0, 0);
            }

        // mask + online softmax (lane-scalar state)
        float p[4][4], mx = -3.0e38f;
#pragma unroll
        for (int ni = 0; ni < 4; ++ni)
#pragma unroll
            for (int r = 0; r < 4; ++r) {
                int j = tb + ni * 16 + quad * 4 + r;
                float v = s[ni][r] * sc;
                bool ok = (j <= qi) && (qi - j < WINDOW);
                v = ok ? v : -3.0e38f;
                p[ni][r] = v;
                mx = fmaxf(mx, v);
            }
        mx = fmaxf(mx, __shfl_xor(mx, 16));
        mx = fmaxf(mx, __shfl_xor(mx, 32));
        const float mn = fmaxf(m_i, mx);
        const float alpha = exp2f(m_i - mn);
        m_i = mn;
        float sum = 0.f;
#pragma unroll
        for (int ni = 0; ni < 4; ++ni)
#pragma unroll
            for (int r = 0; r < 4; ++r) {
                float e = exp2f(p[ni][r] - mn);
                p[ni][r] = e;
                sum += e;
            }
        sum += __shfl_xor(sum, 16);
        sum += __shfl_xor(sum, 32);
        l_i = l_i * alpha + sum;
#pragma unroll
        for (int no = 0; no < 4; ++no) Ov[no] *= alpha;

        // P' -> Ps in A-layout: row = q (rq), cols = 4 consecutive keys
#pragma unroll
        for (int ni = 0; ni < 4; ++ni) {
            ushort4 w4;
            w4.x = f2bfbits(p[ni][0]); w4.y = f2bfbits(p[ni][1]);
            w4.z = f2bfbits(p[ni][2]); w4.w = f2bfbits(p[ni][3]);
            *(ushort4*)&Ps[rq * 72 + ni * 16 + quad * 4] = w4;
        }

        // O' += V^T P^T (swapped): lane gets hd = no*16+quad*4+(0..3), q = qi
#pragma unroll
        for (int kk = 0; kk < 2; ++kk) {
            bf16x8 ap = *(const bf16x8*)&Ps[rq * 72 + kk * 32 + quad * 8];
#pragma unroll
            for (int no = 0; no < 4; ++no) {
                bf16x8 bvv = *(const bf16x8*)&Vt[(no * 16 + l16) * 72 + kk * 32 + quad * 8];
                Ov[no] = __builtin_amdgcn_mfma_f32_16x16x32_bf16(bvv, ap, Ov[no], 0, 0, 0);
            }
        }
        __syncthreads();  // protect Ks/Vt before next tile's staging
    }

    // normalize + vectorized store (4 consecutive hd per reg group)
    const float inv = 1.0f / l_i;
#pragma unroll
    for (int no = 0; no < 4; ++no) {
        ushort4 o;
        o.x = f2bfbits(Ov[no][0] * inv);
        o.y = f2bfbits(Ov[no][1] * inv);
        o.z = f2bfbits(Ov[no][2] * inv);
        o.w = f2bfbits(Ov[no][3] * inv);
        *(ushort4*)((unsigned short*)AO + (size_t)qi * D_MODEL + h * HEAD_DIM +
                    no * 16 + quad * 4) = o;
    }
}

// ---------------------------------------------------------------------------
extern "C" void kernel_launch(void* const* d_in, const int* in_sizes, int n_in,
                              void* d_out, int out_size, void* d_ws, size_t ws_size,
                              hipStream_t stream) {
    const float* x  = (const float*)d_in[0];
    const float* Wq = (const float*)d_in[1];
    const float* Wk = (const float*)d_in[2];
    const float* Wv = (const float*)d_in[3];
    const float* Wo = (const float*)d_in[4];
    const float* bq = (const float*)d_in[5];
    const float* bk = (const float*)d_in[6];
    const float* bv = (const float*)d_in[7];
    const float* bo = (const float*)d_in[8];
    float* out = (float*)d_out;

    char* w = (char*)d_ws;
    const size_t MB = 1u << 20;
    __hip_bfloat16* xb    = (__hip_bfloat16*)(w + 0 * MB);   // 8 MB
    __hip_bfloat16* Wqkvt = (__hip_bfloat16*)(w + 8 * MB);   // 6 MB [3072][1024]
    __hip_bfloat16* Wot   = (__hip_bfloat16*)(w + 14 * MB);  // 2 MB
    float*          bcat  = (float*)(w + 16 * MB);           // 12 KB
    __hip_bfloat16* QKV   = (__hip_bfloat16*)(w + 17 * MB);  // 24 MB [4096][3072]
    __hip_bfloat16* AO    = (__hip_bfloat16*)(w + 41 * MB);  // 8 MB, end 49 MB

    prep_k<<<3073, 256, 0, stream>>>(x, Wq, Wk, Wv, Wo, bq, bk, bv,
                                     (unsigned short*)xb, Wqkvt, Wot, bcat);

    // fused QKV projection: 128x128 tiles, grid (24, 32) = 768 blocks
    dim3 gqkv(QKV_LD / 128, S_LEN / 128);
    gemm_bias_k<128, 128, true><<<gqkv, 256, 0, stream>>>(
        xb, Wqkvt, bcat, QKV, S_LEN, QKV_LD, D_MODEL);

    dim3 ag(S_LEN / 64, N_HEADS);
    attn_k<<<ag, 256, 0, stream>>>(QKV, AO);

    // output projection: 128x64 tiles, grid (16, 32) = 512 blocks
    dim3 go(D_MODEL / 64, S_LEN / 128);
    gemm_bias_k<128, 64, false><<<go, 256, 0, stream>>>(
        AO, Wot, bo, out, S_LEN, D_MODEL, D_MODEL);
}